// Round 1
// baseline (985.141 us; speedup 1.0000x reference)
//
#include <hip/hip_runtime.h>
#include <hip/hip_bf16.h>

// ---------------- constants ----------------
// B=2, L=1024, DM=1024, DI=2048, N=16, K=4, R=64
// M = B*L = 2048 rows
#define MROWS 2048
#define DMOD 1024
#define DINNER 2048
#define NSTATE 16
#define KCONV 4
#define RRANK 64
#define NX 96      // R + 2N
#define NXP 128    // padded

typedef __attribute__((ext_vector_type(8))) short bf16x8;
typedef __attribute__((ext_vector_type(4))) float f32x4;

__device__ inline short f2bf(float f) {
    return (short)__builtin_bit_cast(unsigned short, __float2bfloat16(f));
}

// ---------------- cast fp32 -> bf16 (x) ----------------
__global__ __launch_bounds__(256) void cast_bf16_kernel(const float* __restrict__ in,
                                                        short* __restrict__ out, int n4) {
    int i = blockIdx.x * 256 + threadIdx.x;
    if (i < n4) {
        float4 v = ((const float4*)in)[i];
        short4 o;
        o.x = f2bf(v.x); o.y = f2bf(v.y); o.z = f2bf(v.z); o.w = f2bf(v.w);
        ((short4*)out)[i] = o;
    }
}

// ---------------- transpose + cast: W (Kdim x Ndim) f32 -> WT (NdimP x Kdim) bf16 ----------------
__global__ void transpose_cast_kernel(const float* __restrict__ W, short* __restrict__ WT,
                                      int Kdim, int Ndim, int NdimP) {
    __shared__ float tile[32][33];
    int n0 = blockIdx.x * 32, k0 = blockIdx.y * 32;
    int x = threadIdx.x;
    for (int y = threadIdx.y; y < 32; y += 8) {
        int kk = k0 + y, nn = n0 + x;
        tile[y][x] = (nn < Ndim) ? W[(size_t)kk * Ndim + nn] : 0.f;
    }
    __syncthreads();
    for (int y = threadIdx.y; y < 32; y += 8) {
        int nn = n0 + y, kk = k0 + x;
        if (nn < NdimP) WT[(size_t)nn * Kdim + kk] = f2bf(tile[x][y]);
    }
}

// ---------------- bf16 MFMA GEMM: C(MxNstore,f32) = A(MxK,bf16) * BT(NpadxK,bf16)^T ----------------
#define BM 128
#define BN 128
#define BK 32
#define LDP 40   // LDS pitch in shorts (80B = 5*16B: b128-aligned rows, 2-way-free banks)

__global__ __launch_bounds__(256) void gemm_bf16_kernel(const short* __restrict__ A,
                                                        const short* __restrict__ BT,
                                                        float* __restrict__ C,
                                                        int M, int Kdim, int Nstore) {
    __shared__ __align__(16) short As[BM][LDP];
    __shared__ __align__(16) short Bs[BN][LDP];
    int tid = threadIdx.x;
    int m0 = blockIdx.y * BM, n0 = blockIdx.x * BN;
    int wave = tid >> 6, lane = tid & 63;
    int wr = wave >> 1, wc = wave & 1;
    int lrow = lane & 15, quad = lane >> 4;

    int srow = tid >> 1;          // 0..127
    int scol = (tid & 1) * 16;    // 0 or 16

    const uint4* gA = (const uint4*)(A + (size_t)(m0 + srow) * Kdim + scol);
    const uint4* gB = (const uint4*)(BT + (size_t)(n0 + srow) * Kdim + scol);
    int stepU4 = BK / 8;  // uint4 elements per BK along K

    f32x4 acc[4][4] = {};

    for (int k0 = 0; k0 < Kdim; k0 += BK) {
        uint4 a0 = gA[0], a1 = gA[1];
        uint4 b0 = gB[0], b1 = gB[1];
        gA += stepU4; gB += stepU4;
        *(uint4*)&As[srow][scol]     = a0;
        *(uint4*)&As[srow][scol + 8] = a1;
        *(uint4*)&Bs[srow][scol]     = b0;
        *(uint4*)&Bs[srow][scol + 8] = b1;
        __syncthreads();

        bf16x8 af[4], bfr[4];
#pragma unroll
        for (int i = 0; i < 4; i++)
            af[i] = *(const bf16x8*)&As[wr * 64 + i * 16 + lrow][quad * 8];
#pragma unroll
        for (int j = 0; j < 4; j++)
            bfr[j] = *(const bf16x8*)&Bs[wc * 64 + j * 16 + lrow][quad * 8];
#pragma unroll
        for (int i = 0; i < 4; i++)
#pragma unroll
            for (int j = 0; j < 4; j++)
                acc[i][j] = __builtin_amdgcn_mfma_f32_16x16x32_bf16(af[i], bfr[j], acc[i][j], 0, 0, 0);
        __syncthreads();
    }

#pragma unroll
    for (int i = 0; i < 4; i++) {
#pragma unroll
        for (int j = 0; j < 4; j++) {
            int col = n0 + wc * 64 + j * 16 + lrow;
            if (col < Nstore) {
                int rbase = m0 + wr * 64 + i * 16 + quad * 4;
#pragma unroll
                for (int r = 0; r < 4; r++)
                    C[(size_t)(rbase + r) * Nstore + col] = acc[i][j][r];
            }
        }
    }
}

// ---------------- depthwise causal conv(K=4) + silu, write f32 + bf16 ----------------
__global__ __launch_bounds__(256) void conv_silu_kernel(const float* __restrict__ xz,
                                                        const float* __restrict__ conv_w,
                                                        const float* __restrict__ conv_b,
                                                        float* __restrict__ xconv,
                                                        short* __restrict__ xconv_bf) {
    int idx = blockIdx.x * 256 + threadIdx.x;   // 0 .. 2048*2048-1
    int d = idx & (DINNER - 1);
    int m = idx >> 11;
    int t = m & 1023, b = m >> 10;
    float4 w = *(const float4*)&conv_w[d * 4];
    float acc = conv_b[d];
    int base = b << 10;
#pragma unroll
    for (int j = 0; j < 4; j++) {
        int tt = t - 3 + j;
        if (tt >= 0) {
            float wj = (j == 0) ? w.x : (j == 1) ? w.y : (j == 2) ? w.z : w.w;
            acc += wj * xz[((size_t)(base + tt) << 12) + d];
        }
    }
    float s = acc / (1.f + __expf(-acc));
    xconv[idx] = s;
    xconv_bf[idx] = f2bf(s);
}

// ---------------- conv_cache: xs[:, L-4:, :] -> (B, DI, 4) ----------------
__global__ __launch_bounds__(256) void conv_cache_kernel(const float* __restrict__ xz,
                                                         float* __restrict__ out) {
    int i = blockIdx.x * 256 + threadIdx.x;
    if (i >= 2 * DINNER * KCONV) return;
    int j = i & 3;
    int d = (i >> 2) & (DINNER - 1);
    int b = i >> 13;
    out[i] = xz[((size_t)(b * 1024 + 1020 + j) << 12) + d];
}

// ---------------- dt = softplus(dt_low @ W_dt + b_dt) ; fp32, K=64 ----------------
__global__ __launch_bounds__(256) void dt_kernel(const float* __restrict__ xdbl,   // 2048 x 96
                                                 const float* __restrict__ Wdt,    // 64 x 2048
                                                 const float* __restrict__ bdt,
                                                 float* __restrict__ dt) {         // 2048 x 2048
    __shared__ float dl[16][64];
    int tid = threadIdx.x;
    int m0 = blockIdx.y * 16;
    int d = blockIdx.x * 256 + tid;
    {
        int r = tid >> 4;
        int k = (tid & 15) * 4;
        float4 v = *(const float4*)&xdbl[(size_t)(m0 + r) * NX + k];
        *(float4*)&dl[r][k] = v;
    }
    __syncthreads();
    float acc[16] = {};
    for (int k = 0; k < 64; k++) {
        float w = Wdt[(size_t)k * DINNER + d];
#pragma unroll
        for (int m = 0; m < 16; m++) acc[m] += dl[m][k] * w;
    }
    float bias = bdt[d];
#pragma unroll
    for (int m = 0; m < 16; m++) {
        float v = acc[m] + bias;
        float sp = (v > 20.f) ? v : log1pf(__expf(v));
        dt[(size_t)(m0 + m) * DINNER + d] = sp;
    }
}

// ---------------- selective scan: 16 lanes per (b,d), h in regs, fused gating ----------------
__global__ __launch_bounds__(256) void scan_kernel(const float* __restrict__ dt,
                                                   const float* __restrict__ xconv,
                                                   const float* __restrict__ xdbl,
                                                   const float* __restrict__ xz,
                                                   const float* __restrict__ A_log,
                                                   const float* __restrict__ Dp,
                                                   short* __restrict__ ygate,
                                                   float* __restrict__ hfin) {
    int tid = threadIdx.x;
    int n = tid & 15;
    int c = blockIdx.x * 16 + (tid >> 4);
    int d = c & (DINNER - 1);
    int b = c >> 11;
    float a = -__expf(A_log[d * NSTATE + n]);
    float Dv = Dp[d];
    float h = 0.f;
    size_t rowbase = (size_t)(b << 10);
    for (int t = 0; t < 1024; t++) {
        size_t row = rowbase + t;
        float dtv = dt[(row << 11) + d];
        float u   = xconv[(row << 11) + d];
        float Bn  = xdbl[row * NX + RRANK + n];
        float Cn  = xdbl[row * NX + RRANK + NSTATE + n];
        float zv  = xz[(row << 12) + DINNER + d];
        float ab = __expf(dtv * a);
        h = ab * h + (dtv * u) * Bn;
        float y = h * Cn;
        y += __shfl_xor(y, 1);
        y += __shfl_xor(y, 2);
        y += __shfl_xor(y, 4);
        y += __shfl_xor(y, 8);
        if (n == 0) {
            float sg = zv / (1.f + __expf(-zv));
            ygate[(row << 11) + d] = f2bf((y + Dv * u) * sg);
        }
    }
    hfin[((size_t)c << 4) + n] = h;
}

// ---------------- launch ----------------
extern "C" void kernel_launch(void* const* d_in, const int* in_sizes, int n_in,
                              void* d_out, int out_size, void* d_ws, size_t ws_size,
                              hipStream_t stream) {
    const float* x      = (const float*)d_in[0];   // (2,1024,1024)
    const float* W_in   = (const float*)d_in[1];   // (1024, 4096)
    const float* conv_w = (const float*)d_in[2];   // (2048, 4)
    const float* conv_b = (const float*)d_in[3];   // (2048,)
    const float* W_x    = (const float*)d_in[4];   // (2048, 96)
    const float* W_dt   = (const float*)d_in[5];   // (64, 2048)
    const float* b_dt   = (const float*)d_in[6];   // (2048,)
    const float* A_log  = (const float*)d_in[7];   // (2048, 16)
    const float* D_par  = (const float*)d_in[8];   // (2048,)
    const float* W_out  = (const float*)d_in[9];   // (2048, 1024)

    float* out = (float*)d_out;                         // 2048*1024
    float* hfin = out + 2 * 1024 * 1024;                // 2*2048*16
    float* ccache = hfin + 2 * DINNER * NSTATE;         // 2*2048*4

    char* ws = (char*)d_ws;
    float* xz       = (float*)ws;                 ws += (size_t)MROWS * 4096 * 4;     // 33.5MB
    float* xconv    = (float*)ws;                 ws += (size_t)MROWS * DINNER * 4;   // 16.8MB
    float* dtbuf    = (float*)ws;                 ws += (size_t)MROWS * DINNER * 4;   // 16.8MB
    float* xdbl     = (float*)ws;                 ws += (size_t)MROWS * NX * 4;       // 0.79MB
    short* xconv_bf = (short*)ws;                 ws += (size_t)MROWS * DINNER * 2;   // 8.4MB
    short* ygate    = (short*)ws;                 ws += (size_t)MROWS * DINNER * 2;   // 8.4MB
    short* x_bf     = (short*)ws;                 ws += (size_t)MROWS * DMOD * 2;     // 4.2MB
    short* WinT     = (short*)ws;                 ws += (size_t)4096 * DMOD * 2;      // 8.4MB
    short* WxT      = (short*)ws;                 ws += (size_t)NXP * DINNER * 2;     // 0.52MB
    short* WoutT    = (short*)ws;                 ws += (size_t)DMOD * DINNER * 2;    // 4.2MB

    // 1. casts / transposes
    cast_bf16_kernel<<<(MROWS * DMOD / 4 + 255) / 256, 256, 0, stream>>>(x, x_bf, MROWS * DMOD / 4);
    transpose_cast_kernel<<<dim3(4096 / 32, DMOD / 32), dim3(32, 8), 0, stream>>>(W_in, WinT, DMOD, 4096, 4096);
    transpose_cast_kernel<<<dim3(NXP / 32, DINNER / 32), dim3(32, 8), 0, stream>>>(W_x, WxT, DINNER, NX, NXP);
    transpose_cast_kernel<<<dim3(DMOD / 32, DINNER / 32), dim3(32, 8), 0, stream>>>(W_out, WoutT, DINNER, DMOD, DMOD);

    // 2. xz = x @ W_in   (M=2048, N=4096, K=1024)
    gemm_bf16_kernel<<<dim3(4096 / BN, MROWS / BM), 256, 0, stream>>>(x_bf, WinT, xz, MROWS, DMOD, 4096);

    // 3. causal conv + silu
    conv_silu_kernel<<<MROWS * DINNER / 256, 256, 0, stream>>>(xz, conv_w, conv_b, xconv, xconv_bf);
    conv_cache_kernel<<<(2 * DINNER * KCONV + 255) / 256, 256, 0, stream>>>(xz, ccache);

    // 4. x_dbl = x_conv @ W_x   (M=2048, Npad=128, K=2048, store 96)
    gemm_bf16_kernel<<<dim3(NXP / BN, MROWS / BM), 256, 0, stream>>>(xconv_bf, WxT, xdbl, MROWS, DINNER, NX);

    // 5. dt = softplus(dt_low @ W_dt + b_dt)   (fp32, K=64)
    dt_kernel<<<dim3(DINNER / 256, MROWS / 16), 256, 0, stream>>>(xdbl, W_dt, b_dt, dtbuf);

    // 6. selective scan + gating -> ygate (bf16), h_final
    scan_kernel<<<(2 * DINNER) / 16, 256, 0, stream>>>(dtbuf, xconv, xdbl, xz, A_log, D_par, ygate, hfin);

    // 7. out = y_gated @ W_out   (M=2048, N=1024, K=2048)
    gemm_bf16_kernel<<<dim3(DMOD / BN, MROWS / BM), 256, 0, stream>>>(ygate, WoutT, out, MROWS, DINNER, DMOD);
}

// Round 2
// 360.781 us; speedup vs baseline: 2.7306x; 2.7306x over previous
//
#include <hip/hip_runtime.h>
#include <hip/hip_bf16.h>

// ---------------- constants ----------------
// B=2, L=1024, DM=1024, DI=2048, N=16, K=4, R=64
#define MROWS 2048
#define DMOD 1024
#define DINNER 2048
#define NSTATE 16
#define KCONV 4
#define RRANK 64
#define NX 96      // R + 2N
#define NXP 128    // padded

#define CCH 32     // chunks for the scan
#define TCH 32     // timesteps per chunk (CCH*TCH = 1024)

typedef __attribute__((ext_vector_type(8))) short bf16x8;
typedef __attribute__((ext_vector_type(4))) float f32x4;

__device__ inline short f2bf(float f) {
    return (short)__builtin_bit_cast(unsigned short, __float2bfloat16(f));
}

// ---------------- cast fp32 -> bf16 (x) ----------------
__global__ __launch_bounds__(256) void cast_bf16_kernel(const float* __restrict__ in,
                                                        short* __restrict__ out, int n4) {
    int i = blockIdx.x * 256 + threadIdx.x;
    if (i < n4) {
        float4 v = ((const float4*)in)[i];
        short4 o;
        o.x = f2bf(v.x); o.y = f2bf(v.y); o.z = f2bf(v.z); o.w = f2bf(v.w);
        ((short4*)out)[i] = o;
    }
}

// ---------------- transpose + cast: W (Kdim x Ndim) f32 -> WT (NdimP x Kdim) bf16 ----------------
__global__ void transpose_cast_kernel(const float* __restrict__ W, short* __restrict__ WT,
                                      int Kdim, int Ndim, int NdimP) {
    __shared__ float tile[32][33];
    int n0 = blockIdx.x * 32, k0 = blockIdx.y * 32;
    int x = threadIdx.x;
    for (int y = threadIdx.y; y < 32; y += 8) {
        int kk = k0 + y, nn = n0 + x;
        tile[y][x] = (nn < Ndim) ? W[(size_t)kk * Ndim + nn] : 0.f;
    }
    __syncthreads();
    for (int y = threadIdx.y; y < 32; y += 8) {
        int nn = n0 + y, kk = k0 + x;
        if (nn < NdimP) WT[(size_t)nn * Kdim + kk] = f2bf(tile[x][y]);
    }
}

// ---------------- bf16 MFMA GEMM: C(MxNstore,f32) = A(MxK,bf16) * BT(NpadxK,bf16)^T ----------------
#define BM 128
#define BN 128
#define BK 32
#define LDP 40   // LDS pitch in shorts

__global__ __launch_bounds__(256) void gemm_bf16_kernel(const short* __restrict__ A,
                                                        const short* __restrict__ BT,
                                                        float* __restrict__ C,
                                                        int M, int Kdim, int Nstore) {
    __shared__ __align__(16) short As[BM][LDP];
    __shared__ __align__(16) short Bs[BN][LDP];
    int tid = threadIdx.x;
    int m0 = blockIdx.y * BM, n0 = blockIdx.x * BN;
    int wave = tid >> 6, lane = tid & 63;
    int wr = wave >> 1, wc = wave & 1;
    int lrow = lane & 15, quad = lane >> 4;

    int srow = tid >> 1;          // 0..127
    int scol = (tid & 1) * 16;    // 0 or 16

    const uint4* gA = (const uint4*)(A + (size_t)(m0 + srow) * Kdim + scol);
    const uint4* gB = (const uint4*)(BT + (size_t)(n0 + srow) * Kdim + scol);
    int stepU4 = BK / 8;

    f32x4 acc[4][4] = {};

    for (int k0 = 0; k0 < Kdim; k0 += BK) {
        uint4 a0 = gA[0], a1 = gA[1];
        uint4 b0 = gB[0], b1 = gB[1];
        gA += stepU4; gB += stepU4;
        *(uint4*)&As[srow][scol]     = a0;
        *(uint4*)&As[srow][scol + 8] = a1;
        *(uint4*)&Bs[srow][scol]     = b0;
        *(uint4*)&Bs[srow][scol + 8] = b1;
        __syncthreads();

        bf16x8 af[4], bfr[4];
#pragma unroll
        for (int i = 0; i < 4; i++)
            af[i] = *(const bf16x8*)&As[wr * 64 + i * 16 + lrow][quad * 8];
#pragma unroll
        for (int j = 0; j < 4; j++)
            bfr[j] = *(const bf16x8*)&Bs[wc * 64 + j * 16 + lrow][quad * 8];
#pragma unroll
        for (int i = 0; i < 4; i++)
#pragma unroll
            for (int j = 0; j < 4; j++)
                acc[i][j] = __builtin_amdgcn_mfma_f32_16x16x32_bf16(af[i], bfr[j], acc[i][j], 0, 0, 0);
        __syncthreads();
    }

#pragma unroll
    for (int i = 0; i < 4; i++) {
#pragma unroll
        for (int j = 0; j < 4; j++) {
            int col = n0 + wc * 64 + j * 16 + lrow;
            if (col < Nstore) {
                int rbase = m0 + wr * 64 + i * 16 + quad * 4;
#pragma unroll
                for (int r = 0; r < 4; r++)
                    C[(size_t)(rbase + r) * Nstore + col] = acc[i][j][r];
            }
        }
    }
}

// ---------------- depthwise causal conv(K=4) + silu, write f32 + bf16 ----------------
__global__ __launch_bounds__(256) void conv_silu_kernel(const float* __restrict__ xz,
                                                        const float* __restrict__ conv_w,
                                                        const float* __restrict__ conv_b,
                                                        float* __restrict__ xconv,
                                                        short* __restrict__ xconv_bf) {
    int idx = blockIdx.x * 256 + threadIdx.x;
    int d = idx & (DINNER - 1);
    int m = idx >> 11;
    int t = m & 1023, b = m >> 10;
    float4 w = *(const float4*)&conv_w[d * 4];
    float acc = conv_b[d];
    int base = b << 10;
#pragma unroll
    for (int j = 0; j < 4; j++) {
        int tt = t - 3 + j;
        if (tt >= 0) {
            float wj = (j == 0) ? w.x : (j == 1) ? w.y : (j == 2) ? w.z : w.w;
            acc += wj * xz[((size_t)(base + tt) << 12) + d];
        }
    }
    float s = acc / (1.f + __expf(-acc));
    xconv[idx] = s;
    xconv_bf[idx] = f2bf(s);
}

// ---------------- conv_cache ----------------
__global__ __launch_bounds__(256) void conv_cache_kernel(const float* __restrict__ xz,
                                                         float* __restrict__ out) {
    int i = blockIdx.x * 256 + threadIdx.x;
    if (i >= 2 * DINNER * KCONV) return;
    int j = i & 3;
    int d = (i >> 2) & (DINNER - 1);
    int b = i >> 13;
    out[i] = xz[((size_t)(b * 1024 + 1020 + j) << 12) + d];
}

// ---------------- dt = softplus(dt_low @ W_dt + b_dt) ; fp32, K=64 ----------------
__global__ __launch_bounds__(256) void dt_kernel(const float* __restrict__ xdbl,
                                                 const float* __restrict__ Wdt,
                                                 const float* __restrict__ bdt,
                                                 float* __restrict__ dt) {
    __shared__ float dl[16][64];
    int tid = threadIdx.x;
    int m0 = blockIdx.y * 16;
    int d = blockIdx.x * 256 + tid;
    {
        int r = tid >> 4;
        int k = (tid & 15) * 4;
        float4 v = *(const float4*)&xdbl[(size_t)(m0 + r) * NX + k];
        *(float4*)&dl[r][k] = v;
    }
    __syncthreads();
    float acc[16] = {};
    for (int k = 0; k < 64; k++) {
        float w = Wdt[(size_t)k * DINNER + d];
#pragma unroll
        for (int m = 0; m < 16; m++) acc[m] += dl[m][k] * w;
    }
    float bias = bdt[d];
#pragma unroll
    for (int m = 0; m < 16; m++) {
        float v = acc[m] + bias;
        float sp = (v > 20.f) ? v : log1pf(__expf(v));
        dt[(size_t)(m0 + m) * DINNER + d] = sp;
    }
}

// ---------------- chunked scan, phase 1: per-chunk partials ----------------
// thread i -> chunk = i>>12, ch = i&4095 (ch = b*2048 + d). 16 states in regs.
__global__ __launch_bounds__(256) void scan_phase1_kernel(const float* __restrict__ dt,
                                                          const float* __restrict__ xconv,
                                                          const float* __restrict__ xdbl,
                                                          const float* __restrict__ A_log,
                                                          float* __restrict__ Pbuf,
                                                          float* __restrict__ hpart) {
    int i = blockIdx.x * 256 + threadIdx.x;
    int ch = i & 4095;
    int chunk = i >> 12;
    int d = ch & (DINNER - 1);
    int b = ch >> 11;
    float a[16];
#pragma unroll
    for (int q = 0; q < 4; q++) {
        float4 v = *(const float4*)&A_log[d * 16 + q * 4];
        a[q*4+0] = -__expf(v.x); a[q*4+1] = -__expf(v.y);
        a[q*4+2] = -__expf(v.z); a[q*4+3] = -__expf(v.w);
    }
    float h[16] = {};
    float P[16];
#pragma unroll
    for (int n = 0; n < 16; n++) P[n] = 1.f;
    size_t rowbase = ((size_t)b << 10) + chunk * TCH;
    for (int t = 0; t < TCH; t++) {
        size_t row = rowbase + t;
        float dtv = dt[(row << 11) + d];
        float u   = xconv[(row << 11) + d];
        float du = dtv * u;
        float Bv[16];
#pragma unroll
        for (int q = 0; q < 4; q++)
            *(float4*)&Bv[q*4] = *(const float4*)&xdbl[row * NX + RRANK + q * 4];
#pragma unroll
        for (int n = 0; n < 16; n++) {
            float ab = __expf(dtv * a[n]);
            h[n] = ab * h[n] + du * Bv[n];
            P[n] *= ab;
        }
    }
    size_t o = (size_t)i * 16;
#pragma unroll
    for (int q = 0; q < 4; q++) {
        *(float4*)&hpart[o + q*4] = *(float4*)&h[q*4];
        *(float4*)&Pbuf[o + q*4]  = *(float4*)&P[q*4];
    }
}

// ---------------- chunked scan, phase 2: combine carries across chunks ----------------
// thread i = ch*16 + n (65536 threads)
__global__ __launch_bounds__(256) void scan_combine_kernel(const float* __restrict__ Pbuf,
                                                           const float* __restrict__ hpart,
                                                           float* __restrict__ hin,
                                                           float* __restrict__ hfin) {
    int i = blockIdx.x * 256 + threadIdx.x;
    float carry = 0.f;
    for (int c = 0; c < CCH; c++) {
        size_t idx = ((size_t)c << 16) + i;   // c*65536 + i
        float P  = Pbuf[idx];
        float hp = hpart[idx];
        hin[idx] = carry;
        carry = P * carry + hp;
    }
    hfin[i] = carry;   // hfin[(b*2048+d)*16+n]
}

// ---------------- chunked scan, phase 3: re-run with correct h_in, emit gated y ----------------
__global__ __launch_bounds__(256) void scan_phase3_kernel(const float* __restrict__ dt,
                                                          const float* __restrict__ xconv,
                                                          const float* __restrict__ xdbl,
                                                          const float* __restrict__ xz,
                                                          const float* __restrict__ A_log,
                                                          const float* __restrict__ Dp,
                                                          const float* __restrict__ hin,
                                                          short* __restrict__ ygate) {
    int i = blockIdx.x * 256 + threadIdx.x;
    int ch = i & 4095;
    int chunk = i >> 12;
    int d = ch & (DINNER - 1);
    int b = ch >> 11;
    float a[16];
#pragma unroll
    for (int q = 0; q < 4; q++) {
        float4 v = *(const float4*)&A_log[d * 16 + q * 4];
        a[q*4+0] = -__expf(v.x); a[q*4+1] = -__expf(v.y);
        a[q*4+2] = -__expf(v.z); a[q*4+3] = -__expf(v.w);
    }
    float h[16];
#pragma unroll
    for (int q = 0; q < 4; q++)
        *(float4*)&h[q*4] = *(const float4*)&hin[(size_t)i * 16 + q * 4];
    float Dv = Dp[d];
    size_t rowbase = ((size_t)b << 10) + chunk * TCH;
    for (int t = 0; t < TCH; t++) {
        size_t row = rowbase + t;
        float dtv = dt[(row << 11) + d];
        float u   = xconv[(row << 11) + d];
        float zv  = xz[(row << 12) + DINNER + d];
        float du = dtv * u;
        float Bv[16], Cv[16];
#pragma unroll
        for (int q = 0; q < 4; q++) {
            *(float4*)&Bv[q*4] = *(const float4*)&xdbl[row * NX + RRANK + q * 4];
            *(float4*)&Cv[q*4] = *(const float4*)&xdbl[row * NX + RRANK + NSTATE + q * 4];
        }
        float y = 0.f;
#pragma unroll
        for (int n = 0; n < 16; n++) {
            float ab = __expf(dtv * a[n]);
            h[n] = ab * h[n] + du * Bv[n];
            y += h[n] * Cv[n];
        }
        float sg = zv / (1.f + __expf(-zv));
        ygate[(row << 11) + d] = f2bf((y + Dv * u) * sg);
    }
}

// ---------------- launch ----------------
extern "C" void kernel_launch(void* const* d_in, const int* in_sizes, int n_in,
                              void* d_out, int out_size, void* d_ws, size_t ws_size,
                              hipStream_t stream) {
    const float* x      = (const float*)d_in[0];
    const float* W_in   = (const float*)d_in[1];
    const float* conv_w = (const float*)d_in[2];
    const float* conv_b = (const float*)d_in[3];
    const float* W_x    = (const float*)d_in[4];
    const float* W_dt   = (const float*)d_in[5];
    const float* b_dt   = (const float*)d_in[6];
    const float* A_log  = (const float*)d_in[7];
    const float* D_par  = (const float*)d_in[8];
    const float* W_out  = (const float*)d_in[9];

    float* out = (float*)d_out;
    float* hfin = out + 2 * 1024 * 1024;
    float* ccache = hfin + 2 * DINNER * NSTATE;

    char* ws = (char*)d_ws;
    float* xz       = (float*)ws;                 ws += (size_t)MROWS * 4096 * 4;
    float* xconv    = (float*)ws;                 ws += (size_t)MROWS * DINNER * 4;
    float* dtbuf    = (float*)ws;                 ws += (size_t)MROWS * DINNER * 4;
    float* xdbl     = (float*)ws;                 ws += (size_t)MROWS * NX * 4;
    short* xconv_bf = (short*)ws;                 ws += (size_t)MROWS * DINNER * 2;
    short* ygate    = (short*)ws;                 ws += (size_t)MROWS * DINNER * 2;
    short* x_bf     = (short*)ws;                 ws += (size_t)MROWS * DMOD * 2;
    short* WinT     = (short*)ws;                 ws += (size_t)4096 * DMOD * 2;
    short* WxT      = (short*)ws;                 ws += (size_t)NXP * DINNER * 2;
    short* WoutT    = (short*)ws;                 ws += (size_t)DMOD * DINNER * 2;
    float* Pbuf     = (float*)ws;                 ws += (size_t)CCH * 4096 * 16 * 4;
    float* hpart    = (float*)ws;                 ws += (size_t)CCH * 4096 * 16 * 4;
    float* hinb     = (float*)ws;                 ws += (size_t)CCH * 4096 * 16 * 4;

    // 1. casts / transposes
    cast_bf16_kernel<<<(MROWS * DMOD / 4 + 255) / 256, 256, 0, stream>>>(x, x_bf, MROWS * DMOD / 4);
    transpose_cast_kernel<<<dim3(4096 / 32, DMOD / 32), dim3(32, 8), 0, stream>>>(W_in, WinT, DMOD, 4096, 4096);
    transpose_cast_kernel<<<dim3(NXP / 32, DINNER / 32), dim3(32, 8), 0, stream>>>(W_x, WxT, DINNER, NX, NXP);
    transpose_cast_kernel<<<dim3(DMOD / 32, DINNER / 32), dim3(32, 8), 0, stream>>>(W_out, WoutT, DINNER, DMOD, DMOD);

    // 2. xz = x @ W_in
    gemm_bf16_kernel<<<dim3(4096 / BN, MROWS / BM), 256, 0, stream>>>(x_bf, WinT, xz, MROWS, DMOD, 4096);

    // 3. causal conv + silu
    conv_silu_kernel<<<MROWS * DINNER / 256, 256, 0, stream>>>(xz, conv_w, conv_b, xconv, xconv_bf);
    conv_cache_kernel<<<(2 * DINNER * KCONV + 255) / 256, 256, 0, stream>>>(xz, ccache);

    // 4. x_dbl = x_conv @ W_x
    gemm_bf16_kernel<<<dim3(NXP / BN, MROWS / BM), 256, 0, stream>>>(xconv_bf, WxT, xdbl, MROWS, DINNER, NX);

    // 5. dt
    dt_kernel<<<dim3(DINNER / 256, MROWS / 16), 256, 0, stream>>>(xdbl, W_dt, b_dt, dtbuf);

    // 6. chunked selective scan
    scan_phase1_kernel<<<CCH * 4096 / 256, 256, 0, stream>>>(dtbuf, xconv, xdbl, A_log, Pbuf, hpart);
    scan_combine_kernel<<<4096 * 16 / 256, 256, 0, stream>>>(Pbuf, hpart, hinb, hfin);
    scan_phase3_kernel<<<CCH * 4096 / 256, 256, 0, stream>>>(dtbuf, xconv, xdbl, xz, A_log, D_par, hinb, ygate);

    // 7. out = y_gated @ W_out
    gemm_bf16_kernel<<<dim3(DMOD / BN, MROWS / BM), 256, 0, stream>>>(ygate, WoutT, out, MROWS, DINNER, DMOD);
}

// Round 3
// 297.891 us; speedup vs baseline: 3.3070x; 1.2111x over previous
//
#include <hip/hip_runtime.h>
#include <hip/hip_bf16.h>

// ---------------- constants ----------------
// B=2, L=1024, DM=1024, DI=2048, N=16, K=4, R=64
#define MROWS 2048
#define DMOD 1024
#define DINNER 2048
#define NSTATE 16
#define KCONV 4
#define RRANK 64
#define NX 96      // R + 2N
#define NXP 128    // padded

#define CCH 32     // chunks for the scan
#define TCH 32     // timesteps per chunk (CCH*TCH = 1024)

typedef __attribute__((ext_vector_type(8))) short bf16x8;
typedef __attribute__((ext_vector_type(4))) float f32x4;

__device__ inline short f2bf(float f) {
    return (short)__builtin_bit_cast(unsigned short, __float2bfloat16(f));
}

// ---------------- cast fp32 -> bf16 (x) ----------------
__global__ __launch_bounds__(256) void cast_bf16_kernel(const float* __restrict__ in,
                                                        short* __restrict__ out, int n4) {
    int i = blockIdx.x * 256 + threadIdx.x;
    if (i < n4) {
        float4 v = ((const float4*)in)[i];
        short4 o;
        o.x = f2bf(v.x); o.y = f2bf(v.y); o.z = f2bf(v.z); o.w = f2bf(v.w);
        ((short4*)out)[i] = o;
    }
}

// ---------------- transpose + cast: W (Kdim x Ndim) f32 -> WT (NdimP x Kdim) bf16 ----------------
__global__ void transpose_cast_kernel(const float* __restrict__ W, short* __restrict__ WT,
                                      int Kdim, int Ndim, int NdimP) {
    __shared__ float tile[32][33];
    int n0 = blockIdx.x * 32, k0 = blockIdx.y * 32;
    int x = threadIdx.x;
    for (int y = threadIdx.y; y < 32; y += 8) {
        int kk = k0 + y, nn = n0 + x;
        tile[y][x] = (nn < Ndim) ? W[(size_t)kk * Ndim + nn] : 0.f;
    }
    __syncthreads();
    for (int y = threadIdx.y; y < 32; y += 8) {
        int nn = n0 + y, kk = k0 + x;
        if (nn < NdimP) WT[(size_t)nn * Kdim + kk] = f2bf(tile[x][y]);
    }
}

// ---------------- bf16 MFMA GEMM v2: BM=128, BN=64, BK=32, optional split-K ----------------
// C partial z: C + blockIdx.z * M * Nstore;  each z-slice covers Kper of K.
// grid: (N/64, M/128, splitK)
__global__ __launch_bounds__(256) void gemm_bf16_v2(const short* __restrict__ A,
                                                    const short* __restrict__ BT,
                                                    float* __restrict__ C,
                                                    int M, int Kdim, int Nstore, int Kper) {
    __shared__ __align__(16) short As[128][40];
    __shared__ __align__(16) short Bs[64][40];
    int tid = threadIdx.x;
    int m0 = blockIdx.y * 128, n0 = blockIdx.x * 64;
    int kbase = blockIdx.z * Kper;
    int wave = tid >> 6, lane = tid & 63;
    int wr = wave >> 1, wc = wave & 1;     // wave covers 64 rows x 32 cols
    int lrow = lane & 15, quad = lane >> 4;

    int arow = tid >> 1, acol = (tid & 1) * 16;   // A: 128 rows x 32 k, 32B/thread
    int brow = tid >> 2, bcol = (tid & 3) * 8;    // B: 64 rows x 32 k, 16B/thread

    const uint4* gA = (const uint4*)(A + (size_t)(m0 + arow) * Kdim + kbase + acol);
    const uint4* gB = (const uint4*)(BT + (size_t)(n0 + brow) * Kdim + kbase + bcol);

    f32x4 acc[4][2] = {};

    for (int k0 = 0; k0 < Kper; k0 += 32) {
        uint4 a0 = gA[0], a1 = gA[1];
        uint4 b0 = gB[0];
        gA += 4; gB += 4;
        *(uint4*)&As[arow][acol]     = a0;
        *(uint4*)&As[arow][acol + 8] = a1;
        *(uint4*)&Bs[brow][bcol]     = b0;
        __syncthreads();

        bf16x8 af[4], bf2[2];
#pragma unroll
        for (int i = 0; i < 4; i++)
            af[i] = *(const bf16x8*)&As[wr * 64 + i * 16 + lrow][quad * 8];
#pragma unroll
        for (int j = 0; j < 2; j++)
            bf2[j] = *(const bf16x8*)&Bs[wc * 32 + j * 16 + lrow][quad * 8];
#pragma unroll
        for (int i = 0; i < 4; i++)
#pragma unroll
            for (int j = 0; j < 2; j++)
                acc[i][j] = __builtin_amdgcn_mfma_f32_16x16x32_bf16(af[i], bf2[j], acc[i][j], 0, 0, 0);
        __syncthreads();
    }

    float* Cz = C + (size_t)blockIdx.z * M * Nstore;
#pragma unroll
    for (int i = 0; i < 4; i++) {
#pragma unroll
        for (int j = 0; j < 2; j++) {
            int col = n0 + wc * 32 + j * 16 + lrow;
            if (col < Nstore) {
                int rbase = m0 + wr * 64 + i * 16 + quad * 4;
#pragma unroll
                for (int r = 0; r < 4; r++)
                    Cz[(size_t)(rbase + r) * Nstore + col] = acc[i][j][r];
            }
        }
    }
}

// ---------------- reduce 2 split-K partials (gemm3 -> out) ----------------
__global__ __launch_bounds__(256) void reduce2_kernel(const float* __restrict__ p,
                                                      float* __restrict__ out, int n4) {
    int i = blockIdx.x * 256 + threadIdx.x;
    if (i < n4) {
        float4 a = ((const float4*)p)[i];
        float4 b = ((const float4*)p)[i + n4];
        float4 o;
        o.x = a.x + b.x; o.y = a.y + b.y; o.z = a.z + b.z; o.w = a.w + b.w;
        ((float4*)out)[i] = o;
    }
}

// ---------------- reduce 8 split-K partials (gemm2, 128-col partials -> 96-col xdbl) --------
__global__ __launch_bounds__(256) void reduce8_kernel(const float* __restrict__ p,
                                                      float* __restrict__ xdbl) {
    int i = blockIdx.x * 256 + threadIdx.x;   // over 2048*128
    int c = i & 127;
    int m = i >> 7;
    if (c < NX) {
        float s = 0.f;
#pragma unroll
        for (int kz = 0; kz < 8; kz++)
            s += p[(size_t)kz * MROWS * NXP + i];
        xdbl[(size_t)m * NX + c] = s;
    }
}

// ---------------- depthwise causal conv(K=4) + silu, write f32 + bf16 ----------------
__global__ __launch_bounds__(256) void conv_silu_kernel(const float* __restrict__ xz,
                                                        const float* __restrict__ conv_w,
                                                        const float* __restrict__ conv_b,
                                                        float* __restrict__ xconv,
                                                        short* __restrict__ xconv_bf) {
    int idx = blockIdx.x * 256 + threadIdx.x;
    int d = idx & (DINNER - 1);
    int m = idx >> 11;
    int t = m & 1023, b = m >> 10;
    float4 w = *(const float4*)&conv_w[d * 4];
    float acc = conv_b[d];
    int base = b << 10;
#pragma unroll
    for (int j = 0; j < 4; j++) {
        int tt = t - 3 + j;
        if (tt >= 0) {
            float wj = (j == 0) ? w.x : (j == 1) ? w.y : (j == 2) ? w.z : w.w;
            acc += wj * xz[((size_t)(base + tt) << 12) + d];
        }
    }
    float s = acc / (1.f + __expf(-acc));
    xconv[idx] = s;
    xconv_bf[idx] = f2bf(s);
}

// ---------------- conv_cache ----------------
__global__ __launch_bounds__(256) void conv_cache_kernel(const float* __restrict__ xz,
                                                         float* __restrict__ out) {
    int i = blockIdx.x * 256 + threadIdx.x;
    if (i >= 2 * DINNER * KCONV) return;
    int j = i & 3;
    int d = (i >> 2) & (DINNER - 1);
    int b = i >> 13;
    out[i] = xz[((size_t)(b * 1024 + 1020 + j) << 12) + d];
}

// ---------------- dt = softplus(dt_low @ W_dt + b_dt) ; fp32, K=64 ----------------
__global__ __launch_bounds__(256) void dt_kernel(const float* __restrict__ xdbl,
                                                 const float* __restrict__ Wdt,
                                                 const float* __restrict__ bdt,
                                                 float* __restrict__ dt) {
    __shared__ float dl[16][64];
    int tid = threadIdx.x;
    int m0 = blockIdx.y * 16;
    int d = blockIdx.x * 256 + tid;
    {
        int r = tid >> 4;
        int k = (tid & 15) * 4;
        float4 v = *(const float4*)&xdbl[(size_t)(m0 + r) * NX + k];
        *(float4*)&dl[r][k] = v;
    }
    __syncthreads();
    float acc[16] = {};
    for (int k = 0; k < 64; k++) {
        float w = Wdt[(size_t)k * DINNER + d];
#pragma unroll
        for (int m = 0; m < 16; m++) acc[m] += dl[m][k] * w;
    }
    float bias = bdt[d];
#pragma unroll
    for (int m = 0; m < 16; m++) {
        float v = acc[m] + bias;
        float sp = (v > 20.f) ? v : log1pf(__expf(v));
        dt[(size_t)(m0 + m) * DINNER + d] = sp;
    }
}

// ---------------- chunked scan, phase 1: per-chunk partials ----------------
__global__ __launch_bounds__(256) void scan_phase1_kernel(const float* __restrict__ dt,
                                                          const float* __restrict__ xconv,
                                                          const float* __restrict__ xdbl,
                                                          const float* __restrict__ A_log,
                                                          float* __restrict__ Pbuf,
                                                          float* __restrict__ hpart) {
    int i = blockIdx.x * 256 + threadIdx.x;
    int ch = i & 4095;
    int chunk = i >> 12;
    int d = ch & (DINNER - 1);
    int b = ch >> 11;
    float a[16];
#pragma unroll
    for (int q = 0; q < 4; q++) {
        float4 v = *(const float4*)&A_log[d * 16 + q * 4];
        a[q*4+0] = -__expf(v.x); a[q*4+1] = -__expf(v.y);
        a[q*4+2] = -__expf(v.z); a[q*4+3] = -__expf(v.w);
    }
    float h[16] = {};
    float P[16];
#pragma unroll
    for (int n = 0; n < 16; n++) P[n] = 1.f;
    size_t rowbase = ((size_t)b << 10) + chunk * TCH;
    for (int t = 0; t < TCH; t++) {
        size_t row = rowbase + t;
        float dtv = dt[(row << 11) + d];
        float u   = xconv[(row << 11) + d];
        float du = dtv * u;
        float Bv[16];
#pragma unroll
        for (int q = 0; q < 4; q++)
            *(float4*)&Bv[q*4] = *(const float4*)&xdbl[row * NX + RRANK + q * 4];
#pragma unroll
        for (int n = 0; n < 16; n++) {
            float ab = __expf(dtv * a[n]);
            h[n] = ab * h[n] + du * Bv[n];
            P[n] *= ab;
        }
    }
    size_t o = (size_t)i * 16;
#pragma unroll
    for (int q = 0; q < 4; q++) {
        *(float4*)&hpart[o + q*4] = *(float4*)&h[q*4];
        *(float4*)&Pbuf[o + q*4]  = *(float4*)&P[q*4];
    }
}

// ---------------- chunked scan, phase 2: combine carries across chunks ----------------
__global__ __launch_bounds__(256) void scan_combine_kernel(const float* __restrict__ Pbuf,
                                                           const float* __restrict__ hpart,
                                                           float* __restrict__ hin,
                                                           float* __restrict__ hfin) {
    int i = blockIdx.x * 256 + threadIdx.x;
    float carry = 0.f;
    for (int c = 0; c < CCH; c++) {
        size_t idx = ((size_t)c << 16) + i;
        float P  = Pbuf[idx];
        float hp = hpart[idx];
        hin[idx] = carry;
        carry = P * carry + hp;
    }
    hfin[i] = carry;
}

// ---------------- chunked scan, phase 3: re-run with correct h_in, emit gated y ----------------
__global__ __launch_bounds__(256) void scan_phase3_kernel(const float* __restrict__ dt,
                                                          const float* __restrict__ xconv,
                                                          const float* __restrict__ xdbl,
                                                          const float* __restrict__ xz,
                                                          const float* __restrict__ A_log,
                                                          const float* __restrict__ Dp,
                                                          const float* __restrict__ hin,
                                                          short* __restrict__ ygate) {
    int i = blockIdx.x * 256 + threadIdx.x;
    int ch = i & 4095;
    int chunk = i >> 12;
    int d = ch & (DINNER - 1);
    int b = ch >> 11;
    float a[16];
#pragma unroll
    for (int q = 0; q < 4; q++) {
        float4 v = *(const float4*)&A_log[d * 16 + q * 4];
        a[q*4+0] = -__expf(v.x); a[q*4+1] = -__expf(v.y);
        a[q*4+2] = -__expf(v.z); a[q*4+3] = -__expf(v.w);
    }
    float h[16];
#pragma unroll
    for (int q = 0; q < 4; q++)
        *(float4*)&h[q*4] = *(const float4*)&hin[(size_t)i * 16 + q * 4];
    float Dv = Dp[d];
    size_t rowbase = ((size_t)b << 10) + chunk * TCH;
    for (int t = 0; t < TCH; t++) {
        size_t row = rowbase + t;
        float dtv = dt[(row << 11) + d];
        float u   = xconv[(row << 11) + d];
        float zv  = xz[(row << 12) + DINNER + d];
        float du = dtv * u;
        float Bv[16], Cv[16];
#pragma unroll
        for (int q = 0; q < 4; q++) {
            *(float4*)&Bv[q*4] = *(const float4*)&xdbl[row * NX + RRANK + q * 4];
            *(float4*)&Cv[q*4] = *(const float4*)&xdbl[row * NX + RRANK + NSTATE + q * 4];
        }
        float y = 0.f;
#pragma unroll
        for (int n = 0; n < 16; n++) {
            float ab = __expf(dtv * a[n]);
            h[n] = ab * h[n] + du * Bv[n];
            y += h[n] * Cv[n];
        }
        float sg = zv / (1.f + __expf(-zv));
        ygate[(row << 11) + d] = f2bf((y + Dv * u) * sg);
    }
}

// ---------------- launch ----------------
extern "C" void kernel_launch(void* const* d_in, const int* in_sizes, int n_in,
                              void* d_out, int out_size, void* d_ws, size_t ws_size,
                              hipStream_t stream) {
    const float* x      = (const float*)d_in[0];
    const float* W_in   = (const float*)d_in[1];
    const float* conv_w = (const float*)d_in[2];
    const float* conv_b = (const float*)d_in[3];
    const float* W_x    = (const float*)d_in[4];
    const float* W_dt   = (const float*)d_in[5];
    const float* b_dt   = (const float*)d_in[6];
    const float* A_log  = (const float*)d_in[7];
    const float* D_par  = (const float*)d_in[8];
    const float* W_out  = (const float*)d_in[9];

    float* out = (float*)d_out;
    float* hfin = out + 2 * 1024 * 1024;
    float* ccache = hfin + 2 * DINNER * NSTATE;

    char* ws = (char*)d_ws;
    float* xz       = (float*)ws;                 ws += (size_t)MROWS * 4096 * 4;     // 33.5MB
    float* xconv    = (float*)ws;                 ws += (size_t)MROWS * DINNER * 4;
    float* dtbuf    = (float*)ws;                 ws += (size_t)MROWS * DINNER * 4;
    float* xdbl     = (float*)ws;                 ws += (size_t)MROWS * NX * 4;
    short* xconv_bf = (short*)ws;                 ws += (size_t)MROWS * DINNER * 2;
    short* ygate    = (short*)ws;                 ws += (size_t)MROWS * DINNER * 2;
    short* x_bf     = (short*)ws;                 ws += (size_t)MROWS * DMOD * 2;
    short* WinT     = (short*)ws;                 ws += (size_t)4096 * DMOD * 2;      // 8.4MB
    short* WxT      = (short*)ws;                 ws += (size_t)NXP * DINNER * 2;
    short* WoutT    = (short*)ws;                 ws += (size_t)DMOD * DINNER * 2;
    float* Pbuf     = (float*)ws;                 ws += (size_t)CCH * 4096 * 16 * 4;
    float* hpart    = (float*)ws;                 ws += (size_t)CCH * 4096 * 16 * 4;
    float* hinb     = (float*)ws;                 ws += (size_t)CCH * 4096 * 16 * 4;

    // Split-K partial buffers alias workspace that is dead by the time they're written:
    //  - Cp2 (8 x 2048 x 128 f32 = 8.4MB) aliases WinT (only needed for gemm1, already done).
    //  - Cp3 (2 x 2048 x 1024 f32 = 16.8MB) aliases xz (last read by scan_phase3 / conv_cache,
    //    both complete before gemm3 in stream order).
    float* Cp2 = (float*)WinT;
    float* Cp3 = (float*)xz;

    // 1. casts / transposes
    cast_bf16_kernel<<<(MROWS * DMOD / 4 + 255) / 256, 256, 0, stream>>>(x, x_bf, MROWS * DMOD / 4);
    transpose_cast_kernel<<<dim3(4096 / 32, DMOD / 32), dim3(32, 8), 0, stream>>>(W_in, WinT, DMOD, 4096, 4096);
    transpose_cast_kernel<<<dim3(NXP / 32, DINNER / 32), dim3(32, 8), 0, stream>>>(W_x, WxT, DINNER, NX, NXP);
    transpose_cast_kernel<<<dim3(DMOD / 32, DINNER / 32), dim3(32, 8), 0, stream>>>(W_out, WoutT, DINNER, DMOD, DMOD);

    // 2. xz = x @ W_in   (M=2048, N=4096, K=1024) -> 64x16 = 1024 blocks
    gemm_bf16_v2<<<dim3(4096 / 64, MROWS / 128, 1), 256, 0, stream>>>(x_bf, WinT, xz, MROWS, DMOD, 4096, DMOD);

    // 3. causal conv + silu
    conv_silu_kernel<<<MROWS * DINNER / 256, 256, 0, stream>>>(xz, conv_w, conv_b, xconv, xconv_bf);
    conv_cache_kernel<<<(2 * DINNER * KCONV + 255) / 256, 256, 0, stream>>>(xz, ccache);

    // 4. x_dbl = x_conv @ W_x   (M=2048, N=128pad, K=2048) split-K=8 -> 2x16x8 = 256 blocks
    gemm_bf16_v2<<<dim3(NXP / 64, MROWS / 128, 8), 256, 0, stream>>>(xconv_bf, WxT, Cp2, MROWS, DINNER, NXP, DINNER / 8);
    reduce8_kernel<<<MROWS * NXP / 256, 256, 0, stream>>>(Cp2, xdbl);

    // 5. dt
    dt_kernel<<<dim3(DINNER / 256, MROWS / 16), 256, 0, stream>>>(xdbl, W_dt, b_dt, dtbuf);

    // 6. chunked selective scan
    scan_phase1_kernel<<<CCH * 4096 / 256, 256, 0, stream>>>(dtbuf, xconv, xdbl, A_log, Pbuf, hpart);
    scan_combine_kernel<<<4096 * 16 / 256, 256, 0, stream>>>(Pbuf, hpart, hinb, hfin);
    scan_phase3_kernel<<<CCH * 4096 / 256, 256, 0, stream>>>(dtbuf, xconv, xdbl, xz, A_log, D_par, hinb, ygate);

    // 7. out = y_gated @ W_out   (M=2048, N=1024, K=2048) split-K=2 -> 16x16x2 = 512 blocks
    gemm_bf16_v2<<<dim3(DMOD / 64, MROWS / 128, 2), 256, 0, stream>>>(ygate, WoutT, Cp3, MROWS, DINNER, DMOD, DINNER / 2);
    reduce2_kernel<<<(MROWS * DMOD / 4 + 255) / 256, 256, 0, stream>>>(Cp3, out, MROWS * DMOD / 4);
}

// Round 4
// 292.311 us; speedup vs baseline: 3.3702x; 1.0191x over previous
//
#include <hip/hip_runtime.h>
#include <hip/hip_bf16.h>

// ---------------- constants ----------------
// B=2, L=1024, DM=1024, DI=2048, N=16, K=4, R=64
#define MROWS 2048
#define DMOD 1024
#define DINNER 2048
#define NSTATE 16
#define KCONV 4
#define RRANK 64
#define NX 96      // R + 2N
#define NXP 128    // padded

#define CCH 64     // chunks for the scan
#define TCH 16     // timesteps per chunk (CCH*TCH = 1024)

typedef __attribute__((ext_vector_type(8))) short bf16x8;
typedef __attribute__((ext_vector_type(4))) float f32x4;

__device__ inline short f2bf(float f) {
    return (short)__builtin_bit_cast(unsigned short, __float2bfloat16(f));
}

// ---------------- cast fp32 -> bf16 (x) ----------------
__global__ __launch_bounds__(256) void cast_bf16_kernel(const float* __restrict__ in,
                                                        short* __restrict__ out, int n4) {
    int i = blockIdx.x * 256 + threadIdx.x;
    if (i < n4) {
        float4 v = ((const float4*)in)[i];
        short4 o;
        o.x = f2bf(v.x); o.y = f2bf(v.y); o.z = f2bf(v.z); o.w = f2bf(v.w);
        ((short4*)out)[i] = o;
    }
}

// ---------------- transpose + cast: W (Kdim x Ndim) f32 -> WT (NdimP x Kdim) bf16 ----------------
__global__ void transpose_cast_kernel(const float* __restrict__ W, short* __restrict__ WT,
                                      int Kdim, int Ndim, int NdimP) {
    __shared__ float tile[32][33];
    int n0 = blockIdx.x * 32, k0 = blockIdx.y * 32;
    int x = threadIdx.x;
    for (int y = threadIdx.y; y < 32; y += 8) {
        int kk = k0 + y, nn = n0 + x;
        tile[y][x] = (nn < Ndim) ? W[(size_t)kk * Ndim + nn] : 0.f;
    }
    __syncthreads();
    for (int y = threadIdx.y; y < 32; y += 8) {
        int nn = n0 + y, kk = k0 + x;
        if (nn < NdimP) WT[(size_t)nn * Kdim + kk] = f2bf(tile[x][y]);
    }
}

// ---------------- bf16 MFMA GEMM v2: BM=128, BN=64, BK=32, optional split-K ----------------
__global__ __launch_bounds__(256) void gemm_bf16_v2(const short* __restrict__ A,
                                                    const short* __restrict__ BT,
                                                    float* __restrict__ C,
                                                    int M, int Kdim, int Nstore, int Kper) {
    __shared__ __align__(16) short As[128][40];
    __shared__ __align__(16) short Bs[64][40];
    int tid = threadIdx.x;
    int m0 = blockIdx.y * 128, n0 = blockIdx.x * 64;
    int kbase = blockIdx.z * Kper;
    int wave = tid >> 6, lane = tid & 63;
    int wr = wave >> 1, wc = wave & 1;
    int lrow = lane & 15, quad = lane >> 4;

    int arow = tid >> 1, acol = (tid & 1) * 16;
    int brow = tid >> 2, bcol = (tid & 3) * 8;

    const uint4* gA = (const uint4*)(A + (size_t)(m0 + arow) * Kdim + kbase + acol);
    const uint4* gB = (const uint4*)(BT + (size_t)(n0 + brow) * Kdim + kbase + bcol);

    f32x4 acc[4][2] = {};

    for (int k0 = 0; k0 < Kper; k0 += 32) {
        uint4 a0 = gA[0], a1 = gA[1];
        uint4 b0 = gB[0];
        gA += 4; gB += 4;
        *(uint4*)&As[arow][acol]     = a0;
        *(uint4*)&As[arow][acol + 8] = a1;
        *(uint4*)&Bs[brow][bcol]     = b0;
        __syncthreads();

        bf16x8 af[4], bf2[2];
#pragma unroll
        for (int i = 0; i < 4; i++)
            af[i] = *(const bf16x8*)&As[wr * 64 + i * 16 + lrow][quad * 8];
#pragma unroll
        for (int j = 0; j < 2; j++)
            bf2[j] = *(const bf16x8*)&Bs[wc * 32 + j * 16 + lrow][quad * 8];
#pragma unroll
        for (int i = 0; i < 4; i++)
#pragma unroll
            for (int j = 0; j < 2; j++)
                acc[i][j] = __builtin_amdgcn_mfma_f32_16x16x32_bf16(af[i], bf2[j], acc[i][j], 0, 0, 0);
        __syncthreads();
    }

    float* Cz = C + (size_t)blockIdx.z * M * Nstore;
#pragma unroll
    for (int i = 0; i < 4; i++) {
#pragma unroll
        for (int j = 0; j < 2; j++) {
            int col = n0 + wc * 32 + j * 16 + lrow;
            if (col < Nstore) {
                int rbase = m0 + wr * 64 + i * 16 + quad * 4;
#pragma unroll
                for (int r = 0; r < 4; r++)
                    Cz[(size_t)(rbase + r) * Nstore + col] = acc[i][j][r];
            }
        }
    }
}

// ---------------- reduce 2 split-K partials (gemm3 -> out) ----------------
__global__ __launch_bounds__(256) void reduce2_kernel(const float* __restrict__ p,
                                                      float* __restrict__ out, int n4) {
    int i = blockIdx.x * 256 + threadIdx.x;
    if (i < n4) {
        float4 a = ((const float4*)p)[i];
        float4 b = ((const float4*)p)[i + n4];
        float4 o;
        o.x = a.x + b.x; o.y = a.y + b.y; o.z = a.z + b.z; o.w = a.w + b.w;
        ((float4*)out)[i] = o;
    }
}

// ---------------- reduce 8 split-K partials (gemm2) ----------------
__global__ __launch_bounds__(256) void reduce8_kernel(const float* __restrict__ p,
                                                      float* __restrict__ xdbl) {
    int i = blockIdx.x * 256 + threadIdx.x;
    int c = i & 127;
    int m = i >> 7;
    if (c < NX) {
        float s = 0.f;
#pragma unroll
        for (int kz = 0; kz < 8; kz++)
            s += p[(size_t)kz * MROWS * NXP + i];
        xdbl[(size_t)m * NX + c] = s;
    }
}

// ---------------- depthwise causal conv(K=4) + silu ----------------
__global__ __launch_bounds__(256) void conv_silu_kernel(const float* __restrict__ xz,
                                                        const float* __restrict__ conv_w,
                                                        const float* __restrict__ conv_b,
                                                        float* __restrict__ xconv,
                                                        short* __restrict__ xconv_bf) {
    int idx = blockIdx.x * 256 + threadIdx.x;
    int d = idx & (DINNER - 1);
    int m = idx >> 11;
    int t = m & 1023, b = m >> 10;
    float4 w = *(const float4*)&conv_w[d * 4];
    float acc = conv_b[d];
    int base = b << 10;
#pragma unroll
    for (int j = 0; j < 4; j++) {
        int tt = t - 3 + j;
        if (tt >= 0) {
            float wj = (j == 0) ? w.x : (j == 1) ? w.y : (j == 2) ? w.z : w.w;
            acc += wj * xz[((size_t)(base + tt) << 12) + d];
        }
    }
    float s = acc / (1.f + __expf(-acc));
    xconv[idx] = s;
    xconv_bf[idx] = f2bf(s);
}

// ---------------- conv_cache ----------------
__global__ __launch_bounds__(256) void conv_cache_kernel(const float* __restrict__ xz,
                                                         float* __restrict__ out) {
    int i = blockIdx.x * 256 + threadIdx.x;
    if (i >= 2 * DINNER * KCONV) return;
    int j = i & 3;
    int d = (i >> 2) & (DINNER - 1);
    int b = i >> 13;
    out[i] = xz[((size_t)(b * 1024 + 1020 + j) << 12) + d];
}

// ---------------- dt = softplus(dt_low @ W_dt + b_dt) ; fp32, K=64 ----------------
__global__ __launch_bounds__(256) void dt_kernel(const float* __restrict__ xdbl,
                                                 const float* __restrict__ Wdt,
                                                 const float* __restrict__ bdt,
                                                 float* __restrict__ dt) {
    __shared__ float dl[16][64];
    int tid = threadIdx.x;
    int m0 = blockIdx.y * 16;
    int d = blockIdx.x * 256 + tid;
    {
        int r = tid >> 4;
        int k = (tid & 15) * 4;
        float4 v = *(const float4*)&xdbl[(size_t)(m0 + r) * NX + k];
        *(float4*)&dl[r][k] = v;
    }
    __syncthreads();
    float acc[16] = {};
    for (int k = 0; k < 64; k++) {
        float w = Wdt[(size_t)k * DINNER + d];
#pragma unroll
        for (int m = 0; m < 16; m++) acc[m] += dl[m][k] * w;
    }
    float bias = bdt[d];
#pragma unroll
    for (int m = 0; m < 16; m++) {
        float v = acc[m] + bias;
        float sp = (v > 20.f) ? v : log1pf(__expf(v));
        dt[(size_t)(m0 + m) * DINNER + d] = sp;
    }
}

// ---------------- chunked scan, phase 1: per-chunk partials ----------------
// thread i -> chunk = i>>12, ch = i&4095. P[n] = exp(a[n]*sum_dt) (exact rewrite).
__global__ __launch_bounds__(256) void scan_phase1_kernel(const float* __restrict__ dt,
                                                          const float* __restrict__ xconv,
                                                          const float* __restrict__ xdbl,
                                                          const float* __restrict__ A_log,
                                                          float* __restrict__ Pbuf,
                                                          float* __restrict__ hpart) {
    int i = blockIdx.x * 256 + threadIdx.x;
    int ch = i & 4095;
    int chunk = i >> 12;
    int d = ch & (DINNER - 1);
    int b = ch >> 11;
    float a[16];
#pragma unroll
    for (int q = 0; q < 4; q++) {
        float4 v = *(const float4*)&A_log[d * 16 + q * 4];
        a[q*4+0] = -__expf(v.x); a[q*4+1] = -__expf(v.y);
        a[q*4+2] = -__expf(v.z); a[q*4+3] = -__expf(v.w);
    }
    float h[16] = {};
    float sdt = 0.f;
    size_t rowbase = ((size_t)b << 10) + chunk * TCH;
#pragma unroll 4
    for (int t = 0; t < TCH; t++) {
        size_t row = rowbase + t;
        float dtv = dt[(row << 11) + d];
        float u   = xconv[(row << 11) + d];
        float du = dtv * u;
        float Bv[16];
#pragma unroll
        for (int q = 0; q < 4; q++)
            *(float4*)&Bv[q*4] = *(const float4*)&xdbl[row * NX + RRANK + q * 4];
        sdt += dtv;
#pragma unroll
        for (int n = 0; n < 16; n++) {
            float ab = __expf(dtv * a[n]);
            h[n] = ab * h[n] + du * Bv[n];
        }
    }
    float P[16];
#pragma unroll
    for (int n = 0; n < 16; n++) P[n] = __expf(sdt * a[n]);
    size_t o = (size_t)i * 16;
#pragma unroll
    for (int q = 0; q < 4; q++) {
        *(float4*)&hpart[o + q*4] = *(float4*)&h[q*4];
        *(float4*)&Pbuf[o + q*4]  = *(float4*)&P[q*4];
    }
}

// ---------------- chunked scan, phase 2: combine carries; hin written IN PLACE over Pbuf ----
// Each flat idx is owned by exactly one thread (read P, then overwrite with carry) -> safe.
__global__ __launch_bounds__(256) void scan_combine_kernel(float* __restrict__ Pbuf,
                                                           const float* __restrict__ hpart,
                                                           float* __restrict__ hfin) {
    int i = blockIdx.x * 256 + threadIdx.x;
    float carry = 0.f;
#pragma unroll 8
    for (int c = 0; c < CCH; c++) {
        size_t idx = ((size_t)c << 16) + i;
        float P  = Pbuf[idx];
        float hp = hpart[idx];
        Pbuf[idx] = carry;           // becomes hin
        carry = P * carry + hp;
    }
    hfin[i] = carry;
}

// ---------------- chunked scan, phase 3: re-run with correct h_in, emit gated y ----------------
__global__ __launch_bounds__(256) void scan_phase3_kernel(const float* __restrict__ dt,
                                                          const float* __restrict__ xconv,
                                                          const float* __restrict__ xdbl,
                                                          const float* __restrict__ xz,
                                                          const float* __restrict__ A_log,
                                                          const float* __restrict__ Dp,
                                                          const float* __restrict__ hin,
                                                          short* __restrict__ ygate) {
    int i = blockIdx.x * 256 + threadIdx.x;
    int ch = i & 4095;
    int chunk = i >> 12;
    int d = ch & (DINNER - 1);
    int b = ch >> 11;
    float a[16];
#pragma unroll
    for (int q = 0; q < 4; q++) {
        float4 v = *(const float4*)&A_log[d * 16 + q * 4];
        a[q*4+0] = -__expf(v.x); a[q*4+1] = -__expf(v.y);
        a[q*4+2] = -__expf(v.z); a[q*4+3] = -__expf(v.w);
    }
    float h[16];
#pragma unroll
    for (int q = 0; q < 4; q++)
        *(float4*)&h[q*4] = *(const float4*)&hin[(size_t)i * 16 + q * 4];
    float Dv = Dp[d];
    size_t rowbase = ((size_t)b << 10) + chunk * TCH;
#pragma unroll 4
    for (int t = 0; t < TCH; t++) {
        size_t row = rowbase + t;
        float dtv = dt[(row << 11) + d];
        float u   = xconv[(row << 11) + d];
        float zv  = xz[(row << 12) + DINNER + d];
        float du = dtv * u;
        float Bv[16], Cv[16];
#pragma unroll
        for (int q = 0; q < 4; q++) {
            *(float4*)&Bv[q*4] = *(const float4*)&xdbl[row * NX + RRANK + q * 4];
            *(float4*)&Cv[q*4] = *(const float4*)&xdbl[row * NX + RRANK + NSTATE + q * 4];
        }
        float y = 0.f;
#pragma unroll
        for (int n = 0; n < 16; n++) {
            float ab = __expf(dtv * a[n]);
            h[n] = ab * h[n] + du * Bv[n];
            y += h[n] * Cv[n];
        }
        float sg = zv / (1.f + __expf(-zv));
        ygate[(row << 11) + d] = f2bf((y + Dv * u) * sg);
    }
}

// ---------------- launch ----------------
extern "C" void kernel_launch(void* const* d_in, const int* in_sizes, int n_in,
                              void* d_out, int out_size, void* d_ws, size_t ws_size,
                              hipStream_t stream) {
    const float* x      = (const float*)d_in[0];
    const float* W_in   = (const float*)d_in[1];
    const float* conv_w = (const float*)d_in[2];
    const float* conv_b = (const float*)d_in[3];
    const float* W_x    = (const float*)d_in[4];
    const float* W_dt   = (const float*)d_in[5];
    const float* b_dt   = (const float*)d_in[6];
    const float* A_log  = (const float*)d_in[7];
    const float* D_par  = (const float*)d_in[8];
    const float* W_out  = (const float*)d_in[9];

    float* out = (float*)d_out;
    float* hfin = out + 2 * 1024 * 1024;
    float* ccache = hfin + 2 * DINNER * NSTATE;

    char* ws = (char*)d_ws;
    float* xz       = (float*)ws;                 ws += (size_t)MROWS * 4096 * 4;     // 33.5MB
    float* xconv    = (float*)ws;                 ws += (size_t)MROWS * DINNER * 4;
    float* dtbuf    = (float*)ws;                 ws += (size_t)MROWS * DINNER * 4;
    float* xdbl     = (float*)ws;                 ws += (size_t)MROWS * NX * 4;
    short* xconv_bf = (short*)ws;                 ws += (size_t)MROWS * DINNER * 2;
    short* ygate    = (short*)ws;                 ws += (size_t)MROWS * DINNER * 2;
    short* x_bf     = (short*)ws;                 ws += (size_t)MROWS * DMOD * 2;
    short* WinT     = (short*)ws;                 ws += (size_t)4096 * DMOD * 2;      // 8.4MB
    short* WxT      = (short*)ws;                 ws += (size_t)NXP * DINNER * 2;
    short* WoutT    = (short*)ws;                 ws += (size_t)DMOD * DINNER * 2;
    float* Pbuf     = (float*)ws;                 ws += (size_t)CCH * 4096 * 16 * 4;  // 16.8MB
    float* hpart    = (float*)ws;                 ws += (size_t)CCH * 4096 * 16 * 4;  // 16.8MB

    // Split-K partial aliases (dead regions at their use time):
    float* Cp2 = (float*)WinT;   // gemm2 partials (8MB) over WinT (8MB), WinT dead after gemm1
    float* Cp3 = (float*)xz;     // gemm3 partials (16.8MB) over xz (33.5MB), xz dead after phase3
    float* hinb = Pbuf;          // combine rewrites Pbuf in place as h_in

    // 1. casts / transposes
    cast_bf16_kernel<<<(MROWS * DMOD / 4 + 255) / 256, 256, 0, stream>>>(x, x_bf, MROWS * DMOD / 4);
    transpose_cast_kernel<<<dim3(4096 / 32, DMOD / 32), dim3(32, 8), 0, stream>>>(W_in, WinT, DMOD, 4096, 4096);
    transpose_cast_kernel<<<dim3(NXP / 32, DINNER / 32), dim3(32, 8), 0, stream>>>(W_x, WxT, DINNER, NX, NXP);
    transpose_cast_kernel<<<dim3(DMOD / 32, DINNER / 32), dim3(32, 8), 0, stream>>>(W_out, WoutT, DINNER, DMOD, DMOD);

    // 2. xz = x @ W_in   (1024 blocks)
    gemm_bf16_v2<<<dim3(4096 / 64, MROWS / 128, 1), 256, 0, stream>>>(x_bf, WinT, xz, MROWS, DMOD, 4096, DMOD);

    // 3. causal conv + silu
    conv_silu_kernel<<<MROWS * DINNER / 256, 256, 0, stream>>>(xz, conv_w, conv_b, xconv, xconv_bf);
    conv_cache_kernel<<<(2 * DINNER * KCONV + 255) / 256, 256, 0, stream>>>(xz, ccache);

    // 4. x_dbl = x_conv @ W_x   split-K=8 (256 blocks)
    gemm_bf16_v2<<<dim3(NXP / 64, MROWS / 128, 8), 256, 0, stream>>>(xconv_bf, WxT, Cp2, MROWS, DINNER, NXP, DINNER / 8);
    reduce8_kernel<<<MROWS * NXP / 256, 256, 0, stream>>>(Cp2, xdbl);

    // 5. dt
    dt_kernel<<<dim3(DINNER / 256, MROWS / 16), 256, 0, stream>>>(xdbl, W_dt, b_dt, dtbuf);

    // 6. chunked selective scan (CCH=64 -> 1024 blocks in phases 1/3)
    scan_phase1_kernel<<<CCH * 4096 / 256, 256, 0, stream>>>(dtbuf, xconv, xdbl, A_log, Pbuf, hpart);
    scan_combine_kernel<<<4096 * 16 / 256, 256, 0, stream>>>(Pbuf, hpart, hfin);
    scan_phase3_kernel<<<CCH * 4096 / 256, 256, 0, stream>>>(dtbuf, xconv, xdbl, xz, A_log, D_par, hinb, ygate);

    // 7. out = y_gated @ W_out   split-K=2 (512 blocks)
    gemm_bf16_v2<<<dim3(DMOD / 64, MROWS / 128, 2), 256, 0, stream>>>(ygate, WoutT, Cp3, MROWS, DINNER, DMOD, DINNER / 2);
    reduce2_kernel<<<(MROWS * DMOD / 4 + 255) / 256, 256, 0, stream>>>(Cp3, out, MROWS * DMOD / 4);
}

// Round 5
// 283.468 us; speedup vs baseline: 3.4753x; 1.0312x over previous
//
#include <hip/hip_runtime.h>
#include <hip/hip_bf16.h>

// ---------------- constants ----------------
// B=2, L=1024, DM=1024, DI=2048, N=16, K=4, R=64
#define MROWS 2048
#define DMOD 1024
#define DINNER 2048
#define NSTATE 16
#define KCONV 4
#define RRANK 64
#define NX 96      // R + 2N
#define NXP 128    // padded

#define CCH 64     // chunks for the scan
#define TCH 16     // timesteps per chunk (CCH*TCH = 1024)

typedef __attribute__((ext_vector_type(8))) short bf16x8;
typedef __attribute__((ext_vector_type(4))) float f32x4;

__device__ inline short f2bf(float f) {
    return (short)__builtin_bit_cast(unsigned short, __float2bfloat16(f));
}

// async global->LDS, 16B per lane; LDS dest = wave-uniform base + lane*16
__device__ __forceinline__ void gll16(const void* gp, void* lp) {
    __builtin_amdgcn_global_load_lds(
        (const __attribute__((address_space(1))) void*)gp,
        (__attribute__((address_space(3))) void*)lp, 16, 0, 0);
}

// ---------------- cast fp32 -> bf16 (x) ----------------
__global__ __launch_bounds__(256) void cast_bf16_kernel(const float* __restrict__ in,
                                                        short* __restrict__ out, int n4) {
    int i = blockIdx.x * 256 + threadIdx.x;
    if (i < n4) {
        float4 v = ((const float4*)in)[i];
        short4 o;
        o.x = f2bf(v.x); o.y = f2bf(v.y); o.z = f2bf(v.z); o.w = f2bf(v.w);
        ((short4*)out)[i] = o;
    }
}

// ---------------- transpose + cast: W (Kdim x Ndim) f32 -> WT (NdimP x Kdim) bf16 ----------------
__global__ void transpose_cast_kernel(const float* __restrict__ W, short* __restrict__ WT,
                                      int Kdim, int Ndim, int NdimP) {
    __shared__ float tile[32][33];
    int n0 = blockIdx.x * 32, k0 = blockIdx.y * 32;
    int x = threadIdx.x;
    for (int y = threadIdx.y; y < 32; y += 8) {
        int kk = k0 + y, nn = n0 + x;
        tile[y][x] = (nn < Ndim) ? W[(size_t)kk * Ndim + nn] : 0.f;
    }
    __syncthreads();
    for (int y = threadIdx.y; y < 32; y += 8) {
        int nn = n0 + y, kk = k0 + x;
        if (nn < NdimP) WT[(size_t)nn * Kdim + kk] = f2bf(tile[x][y]);
    }
}

// ---------------- m97-style bf16 MFMA GEMM: BM=128, BN=128, BK=32, global_load_lds ----------------
// grid: (N/128, M/128, splitK); each z covers Kper of K; C partial z at C + z*M*Nstore.
__global__ __launch_bounds__(256) void gemm_m97(const short* __restrict__ A,
                                                const short* __restrict__ BT,
                                                float* __restrict__ C,
                                                int M, int Kdim, int Nstore, int Kper) {
    __shared__ __align__(16) short As[128][32];
    __shared__ __align__(16) short Bs[128][32];
    int tid = threadIdx.x;
    int m0 = blockIdx.y * 128, n0 = blockIdx.x * 128;
    int kbase = blockIdx.z * Kper;
    int wave = tid >> 6, lane = tid & 63;
    int wr = wave >> 1, wc = wave & 1;
    int lrow = lane & 15, quad = lane >> 4;

    // staging: instr c (c=0,1): wave stages rows (c*4+wave)*16 .. +15 (16 rows x 64B = 1KB)
    // lane covers row += lane>>2, kcol = (lane&3)*8 shorts (16B)
    int srow = wave * 16 + (lane >> 2);      // + c*64
    int scol = (lane & 3) * 8;
    const short* gA = A + (size_t)(m0 + srow) * Kdim + kbase + scol;
    const short* gB = BT + (size_t)(n0 + srow) * Kdim + kbase + scol;

    f32x4 acc[4][4] = {};

    for (int k0 = 0; k0 < Kper; k0 += 32) {
#pragma unroll
        for (int c = 0; c < 2; c++) {
            gll16(gA + (size_t)c * 64 * Kdim, &As[(c * 4 + wave) * 16][0]);
            gll16(gB + (size_t)c * 64 * Kdim, &Bs[(c * 4 + wave) * 16][0]);
        }
        gA += 32; gB += 32;
        __syncthreads();   // drains vmcnt (global_load_lds) before LDS reads

        bf16x8 af[4], bf4[4];
#pragma unroll
        for (int i = 0; i < 4; i++)
            af[i] = *(const bf16x8*)&As[wr * 64 + i * 16 + lrow][quad * 8];
#pragma unroll
        for (int j = 0; j < 4; j++)
            bf4[j] = *(const bf16x8*)&Bs[wc * 64 + j * 16 + lrow][quad * 8];
#pragma unroll
        for (int i = 0; i < 4; i++)
#pragma unroll
            for (int j = 0; j < 4; j++)
                acc[i][j] = __builtin_amdgcn_mfma_f32_16x16x32_bf16(af[i], bf4[j], acc[i][j], 0, 0, 0);
        __syncthreads();
    }

    float* Cz = C + (size_t)blockIdx.z * M * Nstore;
#pragma unroll
    for (int i = 0; i < 4; i++) {
#pragma unroll
        for (int j = 0; j < 4; j++) {
            int col = n0 + wc * 64 + j * 16 + lrow;
            if (col < Nstore) {
                int rbase = m0 + wr * 64 + i * 16 + quad * 4;
#pragma unroll
                for (int r = 0; r < 4; r++)
                    Cz[(size_t)(rbase + r) * Nstore + col] = acc[i][j][r];
            }
        }
    }
}

// ---------------- reduce 4 split-K partials (gemm3 -> out) ----------------
__global__ __launch_bounds__(256) void reduce4_kernel(const float* __restrict__ p,
                                                      float* __restrict__ out, int n4) {
    int i = blockIdx.x * 256 + threadIdx.x;
    if (i < n4) {
        float4 o = ((const float4*)p)[i];
#pragma unroll
        for (int z = 1; z < 4; z++) {
            float4 a = ((const float4*)p)[i + (size_t)z * n4];
            o.x += a.x; o.y += a.y; o.z += a.z; o.w += a.w;
        }
        ((float4*)out)[i] = o;
    }
}

// ---------------- reduce 16 split-K partials (gemm2, 128-col partials -> 96-col xdbl) ----------
__global__ __launch_bounds__(256) void reduce16_kernel(const float* __restrict__ p,
                                                       float* __restrict__ xdbl) {
    int i = blockIdx.x * 256 + threadIdx.x;   // over 2048*128
    int c = i & 127;
    int m = i >> 7;
    if (c < NX) {
        float s = 0.f;
#pragma unroll
        for (int kz = 0; kz < 16; kz++)
            s += p[(size_t)kz * MROWS * NXP + i];
        xdbl[(size_t)m * NX + c] = s;
    }
}

// ---------------- depthwise causal conv(K=4) + silu (+fused conv_cache) ----------------
__global__ __launch_bounds__(256) void conv_silu_kernel(const float* __restrict__ xz,
                                                        const float* __restrict__ conv_w,
                                                        const float* __restrict__ conv_b,
                                                        float* __restrict__ xconv,
                                                        short* __restrict__ xconv_bf,
                                                        float* __restrict__ ccache) {
    int idx = blockIdx.x * 256 + threadIdx.x;
    int d = idx & (DINNER - 1);
    int m = idx >> 11;
    int t = m & 1023, b = m >> 10;
    float4 w = *(const float4*)&conv_w[d * 4];
    float acc = conv_b[d];
    int base = b << 10;
#pragma unroll
    for (int j = 0; j < 4; j++) {
        int tt = t - 3 + j;
        if (tt >= 0) {
            float wj = (j == 0) ? w.x : (j == 1) ? w.y : (j == 2) ? w.z : w.w;
            acc += wj * xz[((size_t)(base + tt) << 12) + d];
        }
    }
    float s = acc / (1.f + __expf(-acc));
    xconv[idx] = s;
    xconv_bf[idx] = f2bf(s);
    // fused conv_cache: xs[:, L-4:, :] -> (B, DI, 4)
    if (idx < 2 * DINNER * KCONV) {
        int j = idx & 3;
        int dd = (idx >> 2) & (DINNER - 1);
        int bb = idx >> 13;
        ccache[idx] = xz[((size_t)(bb * 1024 + 1020 + j) << 12) + dd];
    }
}

// ---------------- dt = softplus(dt_low @ W_dt + b_dt) ; fp32, K=64 ----------------
__global__ __launch_bounds__(256) void dt_kernel(const float* __restrict__ xdbl,
                                                 const float* __restrict__ Wdt,
                                                 const float* __restrict__ bdt,
                                                 float* __restrict__ dt) {
    __shared__ float dl[16][64];
    int tid = threadIdx.x;
    int m0 = blockIdx.y * 16;
    int d = blockIdx.x * 256 + tid;
    {
        int r = tid >> 4;
        int k = (tid & 15) * 4;
        float4 v = *(const float4*)&xdbl[(size_t)(m0 + r) * NX + k];
        *(float4*)&dl[r][k] = v;
    }
    __syncthreads();
    float acc[16] = {};
    for (int k = 0; k < 64; k++) {
        float w = Wdt[(size_t)k * DINNER + d];
#pragma unroll
        for (int m = 0; m < 16; m++) acc[m] += dl[m][k] * w;
    }
    float bias = bdt[d];
#pragma unroll
    for (int m = 0; m < 16; m++) {
        float v = acc[m] + bias;
        float sp = (v > 20.f) ? v : log1pf(__expf(v));
        dt[(size_t)(m0 + m) * DINNER + d] = sp;
    }
}

// ---------------- chunked scan, phase 1: per-chunk partials ----------------
__global__ __launch_bounds__(256) void scan_phase1_kernel(const float* __restrict__ dt,
                                                          const float* __restrict__ xconv,
                                                          const float* __restrict__ xdbl,
                                                          const float* __restrict__ A_log,
                                                          float* __restrict__ Pbuf,
                                                          float* __restrict__ hpart) {
    int i = blockIdx.x * 256 + threadIdx.x;
    int ch = i & 4095;
    int chunk = i >> 12;
    int d = ch & (DINNER - 1);
    int b = ch >> 11;
    float a[16];
#pragma unroll
    for (int q = 0; q < 4; q++) {
        float4 v = *(const float4*)&A_log[d * 16 + q * 4];
        a[q*4+0] = -__expf(v.x); a[q*4+1] = -__expf(v.y);
        a[q*4+2] = -__expf(v.z); a[q*4+3] = -__expf(v.w);
    }
    float h[16] = {};
    float sdt = 0.f;
    size_t rowbase = ((size_t)b << 10) + chunk * TCH;
#pragma unroll 4
    for (int t = 0; t < TCH; t++) {
        size_t row = rowbase + t;
        float dtv = dt[(row << 11) + d];
        float u   = xconv[(row << 11) + d];
        float du = dtv * u;
        float Bv[16];
#pragma unroll
        for (int q = 0; q < 4; q++)
            *(float4*)&Bv[q*4] = *(const float4*)&xdbl[row * NX + RRANK + q * 4];
        sdt += dtv;
#pragma unroll
        for (int n = 0; n < 16; n++) {
            float ab = __expf(dtv * a[n]);
            h[n] = ab * h[n] + du * Bv[n];
        }
    }
    float P[16];
#pragma unroll
    for (int n = 0; n < 16; n++) P[n] = __expf(sdt * a[n]);
    size_t o = (size_t)i * 16;
#pragma unroll
    for (int q = 0; q < 4; q++) {
        *(float4*)&hpart[o + q*4] = *(float4*)&h[q*4];
        *(float4*)&Pbuf[o + q*4]  = *(float4*)&P[q*4];
    }
}

// ---------------- chunked scan, phase 2: combine carries; hin written IN PLACE over Pbuf ----
__global__ __launch_bounds__(256) void scan_combine_kernel(float* __restrict__ Pbuf,
                                                           const float* __restrict__ hpart,
                                                           float* __restrict__ hfin) {
    int i = blockIdx.x * 256 + threadIdx.x;
    float carry = 0.f;
#pragma unroll 8
    for (int c = 0; c < CCH; c++) {
        size_t idx = ((size_t)c << 16) + i;
        float P  = Pbuf[idx];
        float hp = hpart[idx];
        Pbuf[idx] = carry;           // becomes hin
        carry = P * carry + hp;
    }
    hfin[i] = carry;
}

// ---------------- chunked scan, phase 3: re-run with correct h_in, emit gated y ----------------
__global__ __launch_bounds__(256) void scan_phase3_kernel(const float* __restrict__ dt,
                                                          const float* __restrict__ xconv,
                                                          const float* __restrict__ xdbl,
                                                          const float* __restrict__ xz,
                                                          const float* __restrict__ A_log,
                                                          const float* __restrict__ Dp,
                                                          const float* __restrict__ hin,
                                                          short* __restrict__ ygate) {
    int i = blockIdx.x * 256 + threadIdx.x;
    int ch = i & 4095;
    int chunk = i >> 12;
    int d = ch & (DINNER - 1);
    int b = ch >> 11;
    float a[16];
#pragma unroll
    for (int q = 0; q < 4; q++) {
        float4 v = *(const float4*)&A_log[d * 16 + q * 4];
        a[q*4+0] = -__expf(v.x); a[q*4+1] = -__expf(v.y);
        a[q*4+2] = -__expf(v.z); a[q*4+3] = -__expf(v.w);
    }
    float h[16];
#pragma unroll
    for (int q = 0; q < 4; q++)
        *(float4*)&h[q*4] = *(const float4*)&hin[(size_t)i * 16 + q * 4];
    float Dv = Dp[d];
    size_t rowbase = ((size_t)b << 10) + chunk * TCH;
#pragma unroll 4
    for (int t = 0; t < TCH; t++) {
        size_t row = rowbase + t;
        float dtv = dt[(row << 11) + d];
        float u   = xconv[(row << 11) + d];
        float zv  = xz[(row << 12) + DINNER + d];
        float du = dtv * u;
        float Bv[16], Cv[16];
#pragma unroll
        for (int q = 0; q < 4; q++) {
            *(float4*)&Bv[q*4] = *(const float4*)&xdbl[row * NX + RRANK + q * 4];
            *(float4*)&Cv[q*4] = *(const float4*)&xdbl[row * NX + RRANK + NSTATE + q * 4];
        }
        float y = 0.f;
#pragma unroll
        for (int n = 0; n < 16; n++) {
            float ab = __expf(dtv * a[n]);
            h[n] = ab * h[n] + du * Bv[n];
            y += h[n] * Cv[n];
        }
        float sg = zv / (1.f + __expf(-zv));
        ygate[(row << 11) + d] = f2bf((y + Dv * u) * sg);
    }
}

// ---------------- launch ----------------
extern "C" void kernel_launch(void* const* d_in, const int* in_sizes, int n_in,
                              void* d_out, int out_size, void* d_ws, size_t ws_size,
                              hipStream_t stream) {
    const float* x      = (const float*)d_in[0];
    const float* W_in   = (const float*)d_in[1];
    const float* conv_w = (const float*)d_in[2];
    const float* conv_b = (const float*)d_in[3];
    const float* W_x    = (const float*)d_in[4];
    const float* W_dt   = (const float*)d_in[5];
    const float* b_dt   = (const float*)d_in[6];
    const float* A_log  = (const float*)d_in[7];
    const float* D_par  = (const float*)d_in[8];
    const float* W_out  = (const float*)d_in[9];

    float* out = (float*)d_out;
    float* hfin = out + 2 * 1024 * 1024;
    float* ccache = hfin + 2 * DINNER * NSTATE;

    char* ws = (char*)d_ws;
    float* xz       = (float*)ws;                 ws += (size_t)MROWS * 4096 * 4;     // 33.5MB
    float* xconv    = (float*)ws;                 ws += (size_t)MROWS * DINNER * 4;
    float* dtbuf    = (float*)ws;                 ws += (size_t)MROWS * DINNER * 4;
    float* xdbl     = (float*)ws;                 ws += (size_t)MROWS * NX * 4;
    short* xconv_bf = (short*)ws;                 ws += (size_t)MROWS * DINNER * 2;
    short* ygate    = (short*)ws;                 ws += (size_t)MROWS * DINNER * 2;
    short* x_bf     = (short*)ws;                 ws += (size_t)MROWS * DMOD * 2;
    short* WinT     = (short*)ws;                 ws += (size_t)4096 * DMOD * 2;      // 8.4MB
    short* WxT      = (short*)ws;                 ws += (size_t)NXP * DINNER * 2;
    short* WoutT    = (short*)ws;                 ws += (size_t)DMOD * DINNER * 2;
    float* Pbuf     = (float*)ws;                 ws += (size_t)CCH * 4096 * 16 * 4;  // 16.8MB
    float* hpart    = (float*)ws;                 ws += (size_t)CCH * 4096 * 16 * 4;  // 16.8MB
    float* Cp2      = (float*)ws;                 ws += (size_t)16 * MROWS * NXP * 4; // 16.8MB

    // gemm3 partials (4 x 2048 x 1024 f32 = 33.5MB) alias xz (33.5MB): xz is dead after
    // scan_phase3, which completes before gemm3 in stream order.
    float* Cp3 = (float*)xz;
    float* hinb = Pbuf;          // combine rewrites Pbuf in place as h_in

    // 1. casts / transposes
    cast_bf16_kernel<<<(MROWS * DMOD / 4 + 255) / 256, 256, 0, stream>>>(x, x_bf, MROWS * DMOD / 4);
    transpose_cast_kernel<<<dim3(4096 / 32, DMOD / 32), dim3(32, 8), 0, stream>>>(W_in, WinT, DMOD, 4096, 4096);
    transpose_cast_kernel<<<dim3(NXP / 32, DINNER / 32), dim3(32, 8), 0, stream>>>(W_x, WxT, DINNER, NX, NXP);
    transpose_cast_kernel<<<dim3(DMOD / 32, DINNER / 32), dim3(32, 8), 0, stream>>>(W_out, WoutT, DINNER, DMOD, DMOD);

    // 2. xz = x @ W_in   (M=2048, N=4096, K=1024) -> 32x16 = 512 blocks
    gemm_m97<<<dim3(4096 / 128, MROWS / 128, 1), 256, 0, stream>>>(x_bf, WinT, xz, MROWS, DMOD, 4096, DMOD);

    // 3. causal conv + silu (+ fused conv_cache)
    conv_silu_kernel<<<MROWS * DINNER / 256, 256, 0, stream>>>(xz, conv_w, conv_b, xconv, xconv_bf, ccache);

    // 4. x_dbl = x_conv @ W_x   (N=128pad, K=2048) split-K=16 -> 1x16x16 = 256 blocks
    gemm_m97<<<dim3(1, MROWS / 128, 16), 256, 0, stream>>>(xconv_bf, WxT, Cp2, MROWS, DINNER, NXP, DINNER / 16);
    reduce16_kernel<<<MROWS * NXP / 256, 256, 0, stream>>>(Cp2, xdbl);

    // 5. dt
    dt_kernel<<<dim3(DINNER / 256, MROWS / 16), 256, 0, stream>>>(xdbl, W_dt, b_dt, dtbuf);

    // 6. chunked selective scan (CCH=64 -> 1024 blocks in phases 1/3)
    scan_phase1_kernel<<<CCH * 4096 / 256, 256, 0, stream>>>(dtbuf, xconv, xdbl, A_log, Pbuf, hpart);
    scan_combine_kernel<<<4096 * 16 / 256, 256, 0, stream>>>(Pbuf, hpart, hfin);
    scan_phase3_kernel<<<CCH * 4096 / 256, 256, 0, stream>>>(dtbuf, xconv, xdbl, xz, A_log, D_par, hinb, ygate);

    // 7. out = y_gated @ W_out   (N=1024, K=2048) split-K=4 -> 8x16x4 = 512 blocks
    gemm_m97<<<dim3(DMOD / 128, MROWS / 128, 4), 256, 0, stream>>>(ygate, WoutT, Cp3, MROWS, DINNER, DMOD, DINNER / 4);
    reduce4_kernel<<<(MROWS * DMOD / 4 + 255) / 256, 256, 0, stream>>>(Cp3, out, MROWS * DMOD / 4);
}